// Round 14
// baseline (6257.631 us; speedup 1.0000x reference)
//
#include <hip/hip_runtime.h>

#define TT 1024
#define HH 256
#define EE 64
#define NC 10
#define SCA __HIP_MEMORY_SCOPE_AGENT
typedef unsigned long long u64;

// R11 k-split pair (passed, 1841us) + staggered poll prefetch.
// Exposure model: peer publish ~950cy + visibility ~500cy => ready ~1450cy;
// R11's single prefetch sampled at ~1400cy (usually stale) then paid 1-2
// serialized ~700cy poll RTs. Fix: second prefetch issued mid-pass-L
// (~1600cy, returns ~2300cy == when needed). Check pv2 -> pv -> spin.
// Exchange stays on the proven sc0sc1 scoped-atomic path (R13 lesson:
// plain-store L2 sharing deadlocks; never again).

#define RED8(A)                                                      \
  do {                                                               \
    _Pragma("unroll")                                                \
    for (int j = 0; j < 4; ++j) {                                    \
      float snd = b0 ? A[j] : A[j + 4];                              \
      float rcv = __shfl_xor(snd, 1, 64);                            \
      A[j] = (b0 ? A[j + 4] : A[j]) + rcv;                           \
    }                                                                \
    _Pragma("unroll")                                                \
    for (int j = 0; j < 2; ++j) {                                    \
      float snd = b1 ? A[j] : A[j + 2];                              \
      float rcv = __shfl_xor(snd, 2, 64);                            \
      A[j] = (b1 ? A[j + 2] : A[j]) + rcv;                           \
    }                                                                \
    {                                                                \
      float snd = b2 ? A[0] : A[1];                                  \
      float rcv = __shfl_xor(snd, 4, 64);                            \
      A[0] = (b2 ? A[1] : A[0]) + rcv;                               \
    }                                                                \
  } while (0)

__global__ __launch_bounds__(512, 2) void lstm_ksp(
    const int* __restrict__ x, const float* __restrict__ emb,
    const float* __restrict__ Wfx, const float* __restrict__ Wfh, const float* __restrict__ bf_,
    const float* __restrict__ Wix, const float* __restrict__ Wih, const float* __restrict__ bi_,
    const float* __restrict__ Wgx, const float* __restrict__ Wgh, const float* __restrict__ bg_,
    const float* __restrict__ Wox, const float* __restrict__ Woh, const float* __restrict__ bo_,
    const float* __restrict__ Wph, const float* __restrict__ Wpb,
    u64* __restrict__ part, float* __restrict__ out)
{
  const int tid = threadIdx.x;
  const int bid = blockIdx.x;
  const int row = bid & 127;
  const int hf  = bid >> 7;
  const int jp  = tid >> 3;            // 0..63
  const int kq  = tid & 7;             // k-slice of 16 within own half
  const int b0 = kq & 1, b1 = (kq >> 1) & 1, b2 = (kq >> 2) & 1;
  const int gate = 2 * b1 + b2;        // this lane's final gate
  const int coff = jp + 64 * b0;       // this lane's final col offset [0,128)
  const int kbase = hf * 128;          // own k range base (== own col base)

  __shared__ __align__(16) float wl[4 * 4 * 512 * 4];  // 128KB LDS weight sets
  __shared__ __align__(16) float hb[2][160];           // own h, padded k+(k>>4)*4
  __shared__ float xp[1536];                           // [v][gate][coff] local
  __shared__ int   xs[TT];
  __shared__ float hp[128];
  __shared__ float pj[NC];

  xs[tid] = x[row * TT + tid];
  xs[tid + 512] = x[row * TT + 512 + tid];

  // x-projection for LOCAL cols only: 3 vocab x 4 gates x 128
  for (int idx = tid; idx < 1536; idx += 512) {
    int v = idx >> 9, r = idx & 511, g = r >> 7, cc = r & 127;
    const float* Wx = (g == 0) ? Wfx : (g == 1) ? Wix : (g == 2) ? Wgx : Wox;
    const float* bb = (g == 0) ? bf_ : (g == 1) ? bi_ : (g == 2) ? bg_ : bo_;
    const int cg = hf * 128 + cc;
    float a = bb[cg];
    const float* ev = emb + v * EE;
#pragma unroll 16
    for (int e = 0; e < EE; ++e) a = fmaf(ev[e], Wx[e * HH + cg], a);
    xp[idx] = a;
  }

  // weight sets: i in [0,16): par=i&1 (0=local col half), gate=(i>>1)&3,
  // cs=(i>>3)&1; col_global = (par ? 1-hf : hf)*128 + 64*cs + jp.
  // regs: r<8 -> i=2r+1 (remote, pass R); r 8..11 -> i=2r-8 (local).
  float wr[12][16];
#pragma unroll
  for (int r = 0; r < 12; ++r) {
    const int i  = (r < 8) ? (2 * r + 1) : (2 * r - 8);
    const int gi = (i >> 1) & 3;
    const int cs = (i >> 3) & 1;
    const int pr = i & 1;
    const float* Wg = (gi == 0) ? Wfh : (gi == 1) ? Wih : (gi == 2) ? Wgh : Woh;
    const int cg = (pr ? (1 - hf) : hf) * 128 + 64 * cs + jp;
#pragma unroll
    for (int kk = 0; kk < 16; ++kk)
      wr[r][kk] = Wg[(kbase + kq * 16 + kk) * HH + cg];
  }
  // LDS sets s=0..3 -> i=2s (local, cs=0, gate=s), lane-linear conflict-free
#pragma unroll
  for (int s = 0; s < 4; ++s) {
    const float* Wg = (s == 0) ? Wfh : (s == 1) ? Wih : (s == 2) ? Wgh : Woh;
    const int cg = hf * 128 + jp;
#pragma unroll
    for (int kk = 0; kk < 16; ++kk)
      wl[(((s * 4 + (kk >> 2)) * 512) + tid) * 4 + (kk & 3)] =
          Wg[(kbase + kq * 16 + kk) * HH + cg];
  }

  if (tid < 160) { hb[0][tid] = 0.f; hb[1][tid] = 0.f; }
  float c = 0.f, hlast = 0.f;
  __syncthreads();

  for (int t = 0; t < TT; ++t) {
    const int cur = t & 1;

    // own-half h slice (16 floats, reused by both passes)
    const float* hq = &hb[cur][kq * 20];
    float hv[16];
    {
      const float4 q0 = *(const float4*)(hq);
      const float4 q1 = *(const float4*)(hq + 4);
      const float4 q2 = *(const float4*)(hq + 8);
      const float4 q3v = *(const float4*)(hq + 12);
      hv[0]=q0.x; hv[1]=q0.y; hv[2]=q0.z; hv[3]=q0.w;
      hv[4]=q1.x; hv[5]=q1.y; hv[6]=q1.z; hv[7]=q1.w;
      hv[8]=q2.x; hv[9]=q2.y; hv[10]=q2.z; hv[11]=q2.w;
      hv[12]=q3v.x; hv[13]=q3v.y; hv[14]=q3v.z; hv[15]=q3v.w;
    }

    // pass R: remote-col partials (reg sets 0..7)
    float aR[8] = {0.f,0.f,0.f,0.f,0.f,0.f,0.f,0.f};
#pragma unroll
    for (int r = 0; r < 8; ++r)
#pragma unroll
      for (int kk = 0; kk < 16; ++kk)
        aR[r] = fmaf(hv[kk], wr[r][kk], aR[r]);
    RED8(aR);                                  // lane holds i=2*q3+1 (remote)

    // publish remote partial early (flight overlaps pass L + peer skew)
    u64* pubp = &part[((u64)cur * 128 + row) * 1024 + (u64)(1 - hf) * 512 + tid];
    __hip_atomic_store(pubp,
        ((u64)(unsigned)(t + 1) << 32) | (u64)__float_as_uint(aR[0]),
        __ATOMIC_RELAXED, SCA);
    // prefetch A (~950cy into step; usually samples just before peer lands)
    const u64* polp = &part[((u64)cur * 128 + row) * 1024 + (u64)hf * 512 + tid];
    u64 pv = 0;
    if (t > 0) pv = __hip_atomic_load(polp, __ATOMIC_RELAXED, SCA);

    // pass L part 1: LDS sets 0..3 (= final q3 0..3)
    float aL[8] = {0.f,0.f,0.f,0.f,0.f,0.f,0.f,0.f};
#pragma unroll
    for (int s = 0; s < 4; ++s)
#pragma unroll
      for (int k4 = 0; k4 < 4; ++k4) {
        const float4 w4 = *(const float4*)&wl[(((s * 4 + k4) * 512) + tid) * 4];
        aL[s] = fmaf(hv[k4 * 4 + 0], w4.x, aL[s]);
        aL[s] = fmaf(hv[k4 * 4 + 1], w4.y, aL[s]);
        aL[s] = fmaf(hv[k4 * 4 + 2], w4.z, aL[s]);
        aL[s] = fmaf(hv[k4 * 4 + 3], w4.w, aL[s]);
      }

    // prefetch B (mid pass-L, ~1600cy; returns ~when finalize runs)
    u64 pv2 = 0;
    if (t > 0) pv2 = __hip_atomic_load(polp, __ATOMIC_RELAXED, SCA);
    __builtin_amdgcn_sched_barrier(0);   // pin issue point (no cross-motion)

    // pass L part 2: reg sets 8..11 (= final q3 4..7)
#pragma unroll
    for (int r = 8; r < 12; ++r)
#pragma unroll
      for (int kk = 0; kk < 16; ++kk)
        aL[r - 4] = fmaf(hv[kk], wr[r][kk], aL[r - 4]);
    RED8(aL);                                  // lane holds i=2*q3 (local)

    // finalize: freshest prefetch first, then spin (per-lane exec-masked)
    float peer = 0.f;
    if (t > 0) {
      const unsigned want = (unsigned)(t + 1);
      u64 got = ((unsigned)(pv2 >> 32) == want) ? pv2 : pv;
      while ((unsigned)(got >> 32) != want)
        got = __hip_atomic_load(polp, __ATOMIC_RELAXED, SCA);
      peer = __uint_as_float((unsigned)got);
    }

    // pre-act -> one activation per thread
    const int v = xs[t];
    const float p = aL[0] + peer + xp[v * 512 + gate * 128 + coff];
    const bool isg = (gate == 2);
    const float pcl = fminf(15.f, fmaxf(-15.f, p));
    const float earg = isg ? (2.f * pcl) : (-p);
    const float ee = __expf(earg);
    const float s = isg ? __fdividef(ee - 1.f, ee + 1.f)
                        : __fdividef(1.f, 1.f + ee);

    // gather i,g,o onto f-lanes (kq<2); update c,h
    const float si = __shfl_xor(s, 4, 64);
    const float sg = __shfl_xor(s, 2, 64);
    const float so = __shfl_xor(s, 6, 64);
    if (kq < 2) {
      c = s * c + si * sg;                     // s == f on these lanes
      const float cx = fminf(15.f, fmaxf(-15.f, c));
      const float ec = __expf(2.f * cx);
      hlast = __fdividef(ec - 1.f, ec + 1.f) * so;
      hb[cur ^ 1][coff + ((coff >> 4) << 2)] = hlast;
    }
    __syncthreads();               // ONE barrier: h(t) ready for next GEMV
  }

  // ---- final h exchange + projection (hf==0 computes output) ----
  if (hf == 1) {
    if (kq < 2)
      __hip_atomic_store(&part[(u64)row * 1024 + coff],
          (3000ull << 32) | (u64)__float_as_uint(hlast), __ATOMIC_RELAXED, SCA);
    return;
  }
  if (tid < 128) {
    const u64* p = &part[(u64)row * 1024 + tid];
    u64 v;
    do { v = __hip_atomic_load(p, __ATOMIC_RELAXED, SCA); }
    while ((unsigned)(v >> 32) != 3000u);
    hp[tid] = __uint_as_float((unsigned)v);
  }
  __syncthreads();
  if (tid < NC) {                  // own h(1023) in hb[0] (t=1023 wrote cur^1=0)
    float a = Wpb[tid];
    for (int k = 0; k < 128; ++k)
      a = fmaf(hb[0][k + ((k >> 4) << 2)], Wph[k * NC + tid], a);
    for (int k = 0; k < 128; ++k)
      a = fmaf(hp[k], Wph[(128 + k) * NC + tid], a);
    pj[tid] = a;
  }
  __syncthreads();
  if (tid < NC) {
    float m = pj[0];
#pragma unroll
    for (int c2 = 1; c2 < NC; ++c2) m = fmaxf(m, pj[c2]);
    float ssum = 0.f;
#pragma unroll
    for (int c2 = 0; c2 < NC; ++c2) ssum += __expf(pj[c2] - m);
    out[row * NC + tid] = pj[tid] - m - __logf(ssum);
  }
}

extern "C" void kernel_launch(void* const* d_in, const int* in_sizes, int n_in,
                              void* d_out, int out_size, void* d_ws, size_t ws_size,
                              hipStream_t stream) {
  (void)in_sizes; (void)n_in; (void)out_size; (void)ws_size;
  const int*   x   = (const int*)d_in[0];
  const float* emb = (const float*)d_in[1];
  const float* Wfx = (const float*)d_in[2];
  const float* Wfh = (const float*)d_in[3];
  const float* bf_ = (const float*)d_in[4];
  const float* Wix = (const float*)d_in[5];
  const float* Wih = (const float*)d_in[6];
  const float* bi_ = (const float*)d_in[7];
  const float* Wgx = (const float*)d_in[8];
  const float* Wgh = (const float*)d_in[9];
  const float* bg_ = (const float*)d_in[10];
  const float* Wox = (const float*)d_in[11];
  const float* Woh = (const float*)d_in[12];
  const float* bo_ = (const float*)d_in[13];
  const float* Wph = (const float*)d_in[14];
  const float* Wpb = (const float*)d_in[15];

  u64* part = (u64*)d_ws;

  // zero both partial slots: 2 x 128 rows x 1024 entries x 8B = 2MB
  hipMemsetAsync(d_ws, 0, 2ull * 128 * 1024 * sizeof(u64), stream);

  hipLaunchKernelGGL(lstm_ksp, dim3(256), dim3(512), 0, stream,
      x, emb, Wfx, Wfh, bf_, Wix, Wih, bi_, Wgx, Wgh, bg_, Wox, Woh, bo_,
      Wph, Wpb, part, (float*)d_out);
}

// Round 15
// 1839.516 us; speedup vs baseline: 3.4018x; 3.4018x over previous
//
#include <hip/hip_runtime.h>

#define TT 1024
#define HH 256
#define EE 64
#define NC 10
#define SCA __HIP_MEMORY_SCOPE_AGENT
typedef unsigned long long u64;
typedef float f32x2 __attribute__((ext_vector_type(2)));

// R11 k-split pair (passed, 1841us) with ONE change: pass R (remote partials,
// the publish-critical path) uses packed fp32 FMA -> publish issues ~400cy
// earlier, so the peer's post-pass-L spin load samples a LANDED value on its
// first try. Pass L stays scalar (long latency cover -- R12 lesson). No loop
// splits, no sched_barrier (R14 lesson). Exchange = proven sc0sc1 scoped
// atomics (R13 lesson).

#define RED8(A)                                                      \
  do {                                                               \
    _Pragma("unroll")                                                \
    for (int j = 0; j < 4; ++j) {                                    \
      float snd = b0 ? A[j] : A[j + 4];                              \
      float rcv = __shfl_xor(snd, 1, 64);                            \
      A[j] = (b0 ? A[j + 4] : A[j]) + rcv;                           \
    }                                                                \
    _Pragma("unroll")                                                \
    for (int j = 0; j < 2; ++j) {                                    \
      float snd = b1 ? A[j] : A[j + 2];                              \
      float rcv = __shfl_xor(snd, 2, 64);                            \
      A[j] = (b1 ? A[j + 2] : A[j]) + rcv;                           \
    }                                                                \
    {                                                                \
      float snd = b2 ? A[0] : A[1];                                  \
      float rcv = __shfl_xor(snd, 4, 64);                            \
      A[0] = (b2 ? A[1] : A[0]) + rcv;                               \
    }                                                                \
  } while (0)

__global__ __launch_bounds__(512, 2) void lstm_kpr(
    const int* __restrict__ x, const float* __restrict__ emb,
    const float* __restrict__ Wfx, const float* __restrict__ Wfh, const float* __restrict__ bf_,
    const float* __restrict__ Wix, const float* __restrict__ Wih, const float* __restrict__ bi_,
    const float* __restrict__ Wgx, const float* __restrict__ Wgh, const float* __restrict__ bg_,
    const float* __restrict__ Wox, const float* __restrict__ Woh, const float* __restrict__ bo_,
    const float* __restrict__ Wph, const float* __restrict__ Wpb,
    u64* __restrict__ part, float* __restrict__ out)
{
  const int tid = threadIdx.x;
  const int bid = blockIdx.x;
  const int row = bid & 127;
  const int hf  = bid >> 7;
  const int jp  = tid >> 3;            // 0..63
  const int kq  = tid & 7;             // k-slice of 16 within own half
  const int b0 = kq & 1, b1 = (kq >> 1) & 1, b2 = (kq >> 2) & 1;
  const int gate = 2 * b1 + b2;        // this lane's final gate
  const int coff = jp + 64 * b0;       // this lane's final col offset [0,128)
  const int kbase = hf * 128;          // own k range base (== own col base)

  __shared__ __align__(16) float wl[4 * 4 * 512 * 4];  // 128KB LDS weight sets
  __shared__ __align__(16) float hb[2][160];           // own h, padded k+(k>>4)*4
  __shared__ float xp[1536];                           // [v][gate][coff] local
  __shared__ int   xs[TT];
  __shared__ float hp[128];
  __shared__ float pj[NC];

  xs[tid] = x[row * TT + tid];
  xs[tid + 512] = x[row * TT + 512 + tid];

  // x-projection for LOCAL cols only: 3 vocab x 4 gates x 128
  for (int idx = tid; idx < 1536; idx += 512) {
    int v = idx >> 9, r = idx & 511, g = r >> 7, cc = r & 127;
    const float* Wx = (g == 0) ? Wfx : (g == 1) ? Wix : (g == 2) ? Wgx : Wox;
    const float* bb = (g == 0) ? bf_ : (g == 1) ? bi_ : (g == 2) ? bg_ : bo_;
    const int cg = hf * 128 + cc;
    float a = bb[cg];
    const float* ev = emb + v * EE;
#pragma unroll 16
    for (int e = 0; e < EE; ++e) a = fmaf(ev[e], Wx[e * HH + cg], a);
    xp[idx] = a;
  }

  // weight sets: i in [0,16): par=i&1 (0=local col half), gate=(i>>1)&3,
  // cs=(i>>3)&1; col_global = (par ? 1-hf : hf)*128 + 64*cs + jp.
  // remote sets (pass R, i=2r+1, r<8): f32x2 k-pairs for v_pk_fma_f32.
  f32x2 wr2[8][8];
#pragma unroll
  for (int r = 0; r < 8; ++r) {
    const int i  = 2 * r + 1;
    const int gi = (i >> 1) & 3;
    const int cs = (i >> 3) & 1;
    const float* Wg = (gi == 0) ? Wfh : (gi == 1) ? Wih : (gi == 2) ? Wgh : Woh;
    const int cg = (1 - hf) * 128 + 64 * cs + jp;
#pragma unroll
    for (int k2 = 0; k2 < 8; ++k2) {
      f32x2 w2 = { Wg[(kbase + kq * 16 + 2 * k2) * HH + cg],
                   Wg[(kbase + kq * 16 + 2 * k2 + 1) * HH + cg] };
      wr2[r][k2] = w2;
    }
  }
  // local reg sets (pass L tail, i=2r-8, r=8..11): scalar
  float wrl[4][16];
#pragma unroll
  for (int r = 8; r < 12; ++r) {
    const int i  = 2 * r - 8;
    const int gi = (i >> 1) & 3;
    const int cs = (i >> 3) & 1;
    const float* Wg = (gi == 0) ? Wfh : (gi == 1) ? Wih : (gi == 2) ? Wgh : Woh;
    const int cg = hf * 128 + 64 * cs + jp;
#pragma unroll
    for (int kk = 0; kk < 16; ++kk)
      wrl[r - 8][kk] = Wg[(kbase + kq * 16 + kk) * HH + cg];
  }
  // LDS sets s=0..3 -> i=2s (local, cs=0, gate=s), lane-linear conflict-free
#pragma unroll
  for (int s = 0; s < 4; ++s) {
    const float* Wg = (s == 0) ? Wfh : (s == 1) ? Wih : (s == 2) ? Wgh : Woh;
    const int cg = hf * 128 + jp;
#pragma unroll
    for (int kk = 0; kk < 16; ++kk)
      wl[(((s * 4 + (kk >> 2)) * 512) + tid) * 4 + (kk & 3)] =
          Wg[(kbase + kq * 16 + kk) * HH + cg];
  }

  if (tid < 160) { hb[0][tid] = 0.f; hb[1][tid] = 0.f; }
  float c = 0.f, hlast = 0.f;
  __syncthreads();

  for (int t = 0; t < TT; ++t) {
    const int cur = t & 1;

    // own-half h slice (16 floats + 8 f32x2 views, reused by both passes)
    const float* hq = &hb[cur][kq * 20];
    float hv[16];
    f32x2 hv2[8];
    {
      const float4 q0 = *(const float4*)(hq);
      const float4 q1 = *(const float4*)(hq + 4);
      const float4 q2 = *(const float4*)(hq + 8);
      const float4 q3v = *(const float4*)(hq + 12);
      hv[0]=q0.x; hv[1]=q0.y; hv[2]=q0.z; hv[3]=q0.w;
      hv[4]=q1.x; hv[5]=q1.y; hv[6]=q1.z; hv[7]=q1.w;
      hv[8]=q2.x; hv[9]=q2.y; hv[10]=q2.z; hv[11]=q2.w;
      hv[12]=q3v.x; hv[13]=q3v.y; hv[14]=q3v.z; hv[15]=q3v.w;
      f32x2 a;
      a[0]=q0.x; a[1]=q0.y; hv2[0]=a;  a[0]=q0.z; a[1]=q0.w; hv2[1]=a;
      a[0]=q1.x; a[1]=q1.y; hv2[2]=a;  a[0]=q1.z; a[1]=q1.w; hv2[3]=a;
      a[0]=q2.x; a[1]=q2.y; hv2[4]=a;  a[0]=q2.z; a[1]=q2.w; hv2[5]=a;
      a[0]=q3v.x; a[1]=q3v.y; hv2[6]=a; a[0]=q3v.z; a[1]=q3v.w; hv2[7]=a;
    }

    // pass R: remote-col partials, PACKED fp32 (publish-critical: ~half wall)
    f32x2 aR2[8];
#pragma unroll
    for (int r = 0; r < 8; ++r) { f32x2 z = {0.f, 0.f}; aR2[r] = z; }
#pragma unroll
    for (int r = 0; r < 8; ++r)
#pragma unroll
      for (int k2 = 0; k2 < 8; ++k2)
        aR2[r] = __builtin_elementwise_fma(hv2[k2], wr2[r][k2], aR2[r]);
    float aR[8];
#pragma unroll
    for (int r = 0; r < 8; ++r) aR[r] = aR2[r][0] + aR2[r][1];
    RED8(aR);                                  // lane holds i=2*q3+1 (remote)

    // publish remote partial early (flight overlaps pass L + peer skew)
    u64* pubp = &part[((u64)cur * 128 + row) * 1024 + (u64)(1 - hf) * 512 + tid];
    __hip_atomic_store(pubp,
        ((u64)(unsigned)(t + 1) << 32) | (u64)__float_as_uint(aR[0]),
        __ATOMIC_RELAXED, SCA);
    // prefetch my local partial's complement from peer
    const u64* polp = &part[((u64)cur * 128 + row) * 1024 + (u64)hf * 512 + tid];
    u64 pv = 0;
    if (t > 0) pv = __hip_atomic_load(polp, __ATOMIC_RELAXED, SCA);

    // pass L: local-col partials, SCALAR (long cover for exchange latency)
    float aL[8] = {0.f,0.f,0.f,0.f,0.f,0.f,0.f,0.f};
#pragma unroll
    for (int s = 0; s < 4; ++s)
#pragma unroll
      for (int k4 = 0; k4 < 4; ++k4) {
        const float4 w4 = *(const float4*)&wl[(((s * 4 + k4) * 512) + tid) * 4];
        aL[s] = fmaf(hv[k4 * 4 + 0], w4.x, aL[s]);
        aL[s] = fmaf(hv[k4 * 4 + 1], w4.y, aL[s]);
        aL[s] = fmaf(hv[k4 * 4 + 2], w4.z, aL[s]);
        aL[s] = fmaf(hv[k4 * 4 + 3], w4.w, aL[s]);
      }
#pragma unroll
    for (int r = 0; r < 4; ++r)
#pragma unroll
      for (int kk = 0; kk < 16; ++kk)
        aL[r + 4] = fmaf(hv[kk], wrl[r][kk], aL[r + 4]);
    RED8(aL);                                  // lane holds i=2*q3 (local)

    // finalize poll (per-lane, exec-masked spin on stragglers only)
    float peer = 0.f;
    if (t > 0) {
      const unsigned want = (unsigned)(t + 1);
      while ((unsigned)(pv >> 32) != want)
        pv = __hip_atomic_load(polp, __ATOMIC_RELAXED, SCA);
      peer = __uint_as_float((unsigned)pv);
    }

    // pre-act -> one activation per thread
    const int v = xs[t];
    const float p = aL[0] + peer + xp[v * 512 + gate * 128 + coff];
    const bool isg = (gate == 2);
    const float pcl = fminf(15.f, fmaxf(-15.f, p));
    const float earg = isg ? (2.f * pcl) : (-p);
    const float ee = __expf(earg);
    const float s = isg ? __fdividef(ee - 1.f, ee + 1.f)
                        : __fdividef(1.f, 1.f + ee);

    // gather i,g,o onto f-lanes (kq<2); update c,h
    const float si = __shfl_xor(s, 4, 64);
    const float sg = __shfl_xor(s, 2, 64);
    const float so = __shfl_xor(s, 6, 64);
    if (kq < 2) {
      c = s * c + si * sg;                     // s == f on these lanes
      const float cx = fminf(15.f, fmaxf(-15.f, c));
      const float ec = __expf(2.f * cx);
      hlast = __fdividef(ec - 1.f, ec + 1.f) * so;
      hb[cur ^ 1][coff + ((coff >> 4) << 2)] = hlast;
    }
    __syncthreads();               // ONE barrier: h(t) ready for next GEMV
  }

  // ---- final h exchange + projection (hf==0 computes output) ----
  if (hf == 1) {
    if (kq < 2)
      __hip_atomic_store(&part[(u64)row * 1024 + coff],
          (3000ull << 32) | (u64)__float_as_uint(hlast), __ATOMIC_RELAXED, SCA);
    return;
  }
  if (tid < 128) {
    const u64* p = &part[(u64)row * 1024 + tid];
    u64 v;
    do { v = __hip_atomic_load(p, __ATOMIC_RELAXED, SCA); }
    while ((unsigned)(v >> 32) != 3000u);
    hp[tid] = __uint_as_float((unsigned)v);
  }
  __syncthreads();
  if (tid < NC) {                  // own h(1023) in hb[0] (t=1023 wrote cur^1=0)
    float a = Wpb[tid];
    for (int k = 0; k < 128; ++k)
      a = fmaf(hb[0][k + ((k >> 4) << 2)], Wph[k * NC + tid], a);
    for (int k = 0; k < 128; ++k)
      a = fmaf(hp[k], Wph[(128 + k) * NC + tid], a);
    pj[tid] = a;
  }
  __syncthreads();
  if (tid < NC) {
    float m = pj[0];
#pragma unroll
    for (int c2 = 1; c2 < NC; ++c2) m = fmaxf(m, pj[c2]);
    float ssum = 0.f;
#pragma unroll
    for (int c2 = 0; c2 < NC; ++c2) ssum += __expf(pj[c2] - m);
    out[row * NC + tid] = pj[tid] - m - __logf(ssum);
  }
}

extern "C" void kernel_launch(void* const* d_in, const int* in_sizes, int n_in,
                              void* d_out, int out_size, void* d_ws, size_t ws_size,
                              hipStream_t stream) {
  (void)in_sizes; (void)n_in; (void)out_size; (void)ws_size;
  const int*   x   = (const int*)d_in[0];
  const float* emb = (const float*)d_in[1];
  const float* Wfx = (const float*)d_in[2];
  const float* Wfh = (const float*)d_in[3];
  const float* bf_ = (const float*)d_in[4];
  const float* Wix = (const float*)d_in[5];
  const float* Wih = (const float*)d_in[6];
  const float* bi_ = (const float*)d_in[7];
  const float* Wgx = (const float*)d_in[8];
  const float* Wgh = (const float*)d_in[9];
  const float* bg_ = (const float*)d_in[10];
  const float* Wox = (const float*)d_in[11];
  const float* Woh = (const float*)d_in[12];
  const float* bo_ = (const float*)d_in[13];
  const float* Wph = (const float*)d_in[14];
  const float* Wpb = (const float*)d_in[15];

  u64* part = (u64*)d_ws;

  // zero both partial slots: 2 x 128 rows x 1024 entries x 8B = 2MB
  hipMemsetAsync(d_ws, 0, 2ull * 128 * 1024 * sizeof(u64), stream);

  hipLaunchKernelGGL(lstm_kpr, dim3(256), dim3(512), 0, stream,
      x, emb, Wfx, Wfh, bf_, Wix, Wih, bi_, Wgx, Wgh, bg_, Wox, Woh, bo_,
      Wph, Wpb, part, (float*)d_out);
}